// Round 8
// baseline (4769.084 us; speedup 1.0000x reference)
//
#include <hip/hip_runtime.h>

#define LSEQ 2048
#define TAGS 12

typedef _Float16 half2v __attribute__((ext_vector_type(2)));
typedef unsigned u32x4 __attribute__((ext_vector_type(4)));
typedef unsigned long long u64;

__device__ __forceinline__ float sigm(float x){ return 1.0f/(1.0f+__expf(-x)); }
__device__ __forceinline__ float tanh_fast(float x){ return 1.0f - 2.0f/(1.0f+__expf(2.0f*x)); }
__device__ __forceinline__ half2v pack2(float a, float b){
  half2v r; r.x=(_Float16)a; r.y=(_Float16)b; return r;
}
__device__ __forceinline__ half2v h2(unsigned u){ return __builtin_bit_cast(half2v, u); }

// Raw workgroup barrier: orders LDS only (lgkmcnt), does NOT drain vmcnt
// (publish atomics + xg prefetch stay in flight across it).
__device__ __forceinline__ void wg_barrier(){
  asm volatile("s_waitcnt lgkmcnt(0)" ::: "memory");
  __builtin_amdgcn_s_barrier();
  __builtin_amdgcn_sched_barrier(0);
  asm volatile("" ::: "memory");
}

// K0: zero the exchange buffer (tag 0 never matches step tags in [1,2047]).
__global__ void init_kernel(u64* ex)
{
  int tid = blockIdx.x*256 + threadIdx.x;
  if (tid < 1024) ex[tid] = 0ull;
}

// K1: xg[d][t][row] = b_ih[row]+b_hh[row] + sum_e embed[sent[t]][e] * w_ih[row][e]
__global__ void xg_kernel(
    const int* sent, const float* embed,
    const float* w_ih_f, const float* b_ih_f, const float* b_hh_f,
    const float* w_ih_b, const float* b_ih_b, const float* b_hh_b,
    float* xg)
{
  __shared__ float x_sh[8][256];
  int tid = threadIdx.x;
  int t0 = blockIdx.x * 8;
  for (int i=0;i<8;++i){
    int idx = sent[t0+i];
    x_sh[i][tid] = embed[(size_t)idx*256 + tid];
  }
  __syncthreads();
  for (int ri=0; ri<8; ++ri){
    int r = ri*256 + tid;
    int d = r >> 10;
    int row = r & 1023;
    const float* wr = (d ? w_ih_b : w_ih_f) + (size_t)row*256;
    const float* bi = d ? b_ih_b : b_ih_f;
    const float* bh = d ? b_hh_b : b_hh_f;
    float acc[8];
    #pragma unroll
    for (int i=0;i<8;++i) acc[i]=0.f;
    for (int k0=0;k0<256;k0+=4){
      float4 p = *(const float4*)(wr + k0);
      #pragma unroll
      for (int i=0;i<8;++i){
        acc[i] += p.x*x_sh[i][k0] + p.y*x_sh[i][k0+1]
                + p.z*x_sh[i][k0+2] + p.w*x_sh[i][k0+3];
      }
    }
    float bias = bi[row] + bh[row];
    #pragma unroll
    for (int i=0;i<8;++i)
      xg[((size_t)d*LSEQ + (size_t)(t0+i))*1024 + row] = acc[i] + bias;
  }
}

// K2: bidirectional LSTM recurrence — RESTRUCTURED: 2 CUs per direction.
// Rounds 0-7 (all ~2770-2910 us) proved: inter-CU signaling has a hard
// ~1000+cy floor regardless of mechanism (barriers r0-r2, sc0 loads r3,
// XCD atomics r4, cold rings r5, election r6, hot rings r7). With 4 CUs the
// exchange RT dominates the 3400cy step. Fix is structural:
//  - 2 CUs/dir x 256 threads, 2 gate-rows/thread (512 rows/CU). The 128
//    h readlanes/step are SHARED by both rows -> VALU ~940cy/step at
//    1 wave/SIMD (launch_bounds(256,1): full issue BW, no co-resident wave).
//  - weights: 80 pairs/row in VGPRs (160 regs, under the 256 addressable
//    cap; >256 = AGPR shuttling disaster) + 48 pairs/row streamed from LDS
//    (98KB; [group][row][4] layout -> 16B lane stride -> conflict-free
//    ds_read_b128).
//  - exchange: ONE peer, 64 pairs, via the r2-PROVEN pair (atomicExch
//    publish, agent-scope relaxed load poll). All sc0/ring/election
//    machinery deleted (never helped; r7's 43ms outlier came from it).
//    RT now hides under the ~2x longer local phase.
//  - same 2-light-barrier scheme, parity-buffered gate_sh/h2rem,
//    replicated update (hp stays in registers for readlane).
// Parity-slot safety (2-CU induction): we publish tag s+1 only after
// consuming peer's s; peer consumed our s-1 strictly before publishing s;
// so overwriting the (s+1)&1 slot (stale tag s-1) is safe.
__global__ __launch_bounds__(256,1) void lstm_rec(
    const float* __restrict__ w_hh_f, const float* __restrict__ w_hh_b,
    const float* __restrict__ xg, unsigned short* __restrict__ hstH,
    u64* __restrict__ ex)
{
  int blk = blockIdx.x;
  int d = blk & 7;
  if (d > 1) return;
  int c = blk >> 3;                  // CU within direction: 0 or 1
  int tid = threadIdx.x;
  int uu = tid & 127;                // unit within CU's 128
  int gp = tid >> 7;                 // 0: gates (i,g), 1: gates (f,o)
  int l  = tid & 63;
  int u  = 128*c + uu;               // global unit
  int row0 = gp*256 + u;             // gate gp   (i or f) - sigmoid
  int row1 = (gp+2)*256 + u;         // gate gp+2 (g or o)
  int lr0 = gp*128 + uu;             // local row ids [0,512)
  int lr1 = (gp+2)*128 + uu;
  const float* W = d ? w_hh_b : w_hh_f;
  const float* xgd = xg + (size_t)d*LSEQ*1024;
  unsigned short* hd = hstH + (size_t)d*LSEQ*256;
  u64* exd = ex + (size_t)d*256;     // [2 parity][2 cu][64 pairs]

  __shared__ unsigned wlds[12][512][4];  // 98.3 KB: peer pairs 16..63
  __shared__ float gate_sh[2][512];      // parity x [gate*128+uu]
  __shared__ unsigned h2rem[2][64];      // parity x peer h-pairs

  // Register weights: permuted pair order [own 0..63 | peer 0..15].
  half2v wA[80], wB[80];
  {
    const float* pr0 = W + (size_t)row0*256;
    const float* pr1 = W + (size_t)row1*256;
    int ob = 128*c, pb = 128*(1-c);
    #pragma unroll
    for (int k2=0;k2<32;++k2){           // own pairs 0..63
      float4 a = *(const float4*)(pr0 + ob + 4*k2);
      wA[2*k2] = pack2(a.x,a.y); wA[2*k2+1] = pack2(a.z,a.w);
      float4 b = *(const float4*)(pr1 + ob + 4*k2);
      wB[2*k2] = pack2(b.x,b.y); wB[2*k2+1] = pack2(b.z,b.w);
    }
    #pragma unroll
    for (int k2=0;k2<8;++k2){            // peer pairs 0..15
      float4 a = *(const float4*)(pr0 + pb + 4*k2);
      wA[64+2*k2] = pack2(a.x,a.y); wA[64+2*k2+1] = pack2(a.z,a.w);
      float4 b = *(const float4*)(pr1 + pb + 4*k2);
      wB[64+2*k2] = pack2(b.x,b.y); wB[64+2*k2+1] = pack2(b.z,b.w);
    }
    // LDS weights: peer pairs 16..63 (cols pb+32 .. pb+127), 12 groups of 4
    for (int jg=0;jg<12;++jg){
      float4 a0 = *(const float4*)(pr0 + pb + 32 + 8*jg);
      float4 a1 = *(const float4*)(pr0 + pb + 32 + 8*jg + 4);
      wlds[jg][lr0][0] = __builtin_bit_cast(unsigned, pack2(a0.x,a0.y));
      wlds[jg][lr0][1] = __builtin_bit_cast(unsigned, pack2(a0.z,a0.w));
      wlds[jg][lr0][2] = __builtin_bit_cast(unsigned, pack2(a1.x,a1.y));
      wlds[jg][lr0][3] = __builtin_bit_cast(unsigned, pack2(a1.z,a1.w));
      float4 b0 = *(const float4*)(pr1 + pb + 32 + 8*jg);
      float4 b1 = *(const float4*)(pr1 + pb + 32 + 8*jg + 4);
      wlds[jg][lr1][0] = __builtin_bit_cast(unsigned, pack2(b0.x,b0.y));
      wlds[jg][lr1][1] = __builtin_bit_cast(unsigned, pack2(b0.z,b0.w));
      wlds[jg][lr1][2] = __builtin_bit_cast(unsigned, pack2(b1.x,b1.y));
      wlds[jg][lr1][3] = __builtin_bit_cast(unsigned, pack2(b1.z,b1.w));
    }
  }
  if (tid < 128) h2rem[tid>>6][tid&63] = 0u;
  float c0 = 0.f, c1 = 0.f;          // cell state, local pair l (replicated)
  unsigned hp = 0u;                  // own h-pair l, replicated all lanes
  bool is_pub  = (tid < 64);         // wave0: publish + history
  bool is_poll = (tid >= 64) && (tid < 128);   // wave1: poll peer
  __syncthreads();

  int tf = d ? (LSEQ-1) : 0;
  float xga = xgd[(size_t)tf*1024 + row0];
  float xgb = xgd[(size_t)tf*1024 + row1];

  for (int s=0;s<LSEQ;++s){
    int par = s & 1;
    bool p = is_poll && (s > 0);
    // --- poller: issue first probe early (hides under the local half-dot)
    u64 v0 = 0ull;
    if (p)
      v0 = __hip_atomic_load(&exd[par*128 + (1-c)*64 + l],
                             __ATOMIC_RELAXED, __HIP_MEMORY_SCOPE_AGENT);
    // --- local half: own 64 pairs from registers (lane k holds pair k)
    float a0 = xga, a1 = xgb, b0 = 0.f, b1 = 0.f;
    #pragma unroll
    for (int k=0;k<64;k+=2){
      unsigned h0v = __builtin_amdgcn_readlane(hp, k);
      unsigned h1v = __builtin_amdgcn_readlane(hp, k+1);
      a0 = __builtin_amdgcn_fdot2(h2(h0v), wA[k],   a0, false);
      a1 = __builtin_amdgcn_fdot2(h2(h0v), wB[k],   a1, false);
      b0 = __builtin_amdgcn_fdot2(h2(h1v), wA[k+1], b0, false);
      b1 = __builtin_amdgcn_fdot2(h2(h1v), wB[k+1], b1, false);
    }
    // --- xg prefetch (fire-and-forget; counted wait lands next step)
    int tn = (s+1 < LSEQ) ? (d ? (LSEQ-2-s) : (s+1)) : tf;
    float nxa = xgd[(size_t)tn*1024 + row0];
    float nxb = xgd[(size_t)tn*1024 + row1];
    // --- finish poll (proven agent-scope spin), write peer pairs to LDS
    if (p){
      u64 v = v0;
      while ((unsigned)(v>>32) != (unsigned)s)
        v = __hip_atomic_load(&exd[par*128 + (1-c)*64 + l],
                              __ATOMIC_RELAXED, __HIP_MEMORY_SCOPE_AGENT);
      h2rem[par][l] = (unsigned)v;
    }
    wg_barrier();                    // #1: poller LDS writes -> all waves
    unsigned hr = h2rem[par][l];     // lane k holds peer pair k
    // --- remote half, register part: peer pairs 0..15
    #pragma unroll
    for (int k=0;k<16;k+=2){
      unsigned h0v = __builtin_amdgcn_readlane(hr, k);
      unsigned h1v = __builtin_amdgcn_readlane(hr, k+1);
      a0 = __builtin_amdgcn_fdot2(h2(h0v), wA[64+k],   a0, false);
      a1 = __builtin_amdgcn_fdot2(h2(h0v), wB[64+k],   a1, false);
      b0 = __builtin_amdgcn_fdot2(h2(h1v), wA[64+k+1], b0, false);
      b1 = __builtin_amdgcn_fdot2(h2(h1v), wB[64+k+1], b1, false);
    }
    // --- remote half, LDS part: peer pairs 16..63 (ds_read_b128 x2/group)
    #pragma unroll
    for (int jg=0;jg<12;++jg){
      u32x4 ga = *(const u32x4*)&wlds[jg][lr0][0];
      u32x4 gb = *(const u32x4*)&wlds[jg][lr1][0];
      unsigned h0v = __builtin_amdgcn_readlane(hr, 16+4*jg);
      unsigned h1v = __builtin_amdgcn_readlane(hr, 17+4*jg);
      unsigned h2v = __builtin_amdgcn_readlane(hr, 18+4*jg);
      unsigned h3v = __builtin_amdgcn_readlane(hr, 19+4*jg);
      a0 = __builtin_amdgcn_fdot2(h2(h0v), h2(ga[0]), a0, false);
      a1 = __builtin_amdgcn_fdot2(h2(h0v), h2(gb[0]), a1, false);
      b0 = __builtin_amdgcn_fdot2(h2(h1v), h2(ga[1]), b0, false);
      b1 = __builtin_amdgcn_fdot2(h2(h1v), h2(gb[1]), b1, false);
      a0 = __builtin_amdgcn_fdot2(h2(h2v), h2(ga[2]), a0, false);
      a1 = __builtin_amdgcn_fdot2(h2(h2v), h2(gb[2]), a1, false);
      b0 = __builtin_amdgcn_fdot2(h2(h3v), h2(ga[3]), b0, false);
      b1 = __builtin_amdgcn_fdot2(h2(h3v), h2(gb[3]), b1, false);
    }
    float pre0 = a0 + b0, pre1 = a1 + b1;
    float act0 = sigm(pre0);                               // i or f
    float act1 = (gp==0) ? tanh_fast(pre1) : sigm(pre1);   // g or o
    gate_sh[par][gp*128 + uu]     = act0;
    gate_sh[par][(gp+2)*128 + uu] = act1;
    wg_barrier();                    // #2: gate writes -> update reads
    // --- update, replicated on ALL lanes (deterministic -> identical hp)
    {
      const float* gpt = gate_sh[par];
      float2 gi = *(const float2*)&gpt[      2*l];
      float2 gf = *(const float2*)&gpt[128 + 2*l];
      float2 gg = *(const float2*)&gpt[256 + 2*l];
      float2 go = *(const float2*)&gpt[384 + 2*l];
      c0 = gf.x*c0 + gi.x*gg.x;
      c1 = gf.y*c1 + gi.y*gg.y;
      float h0 = go.x * tanh_fast(c0);
      float h1 = go.y * tanh_fast(c1);
      hp = __builtin_bit_cast(unsigned, pack2(h0,h1));
    }
    // --- wave0: publish h(s) tagged s+1 (fire-and-forget atomicExch —
    //     the PROVEN device-coherent primitive) + h history store.
    if (is_pub){
      if (s+1 < LSEQ)
        atomicExch(&exd[(((s+1)&1))*128 + c*64 + l],
                   ((u64)(unsigned)(s+1) << 32) | (u64)hp);
      int tp = d ? (LSEQ-1-s) : s;
      *(unsigned*)&hd[(size_t)tp*256 + 128*c + 2*l] = hp;
    }
    xga = nxa; xgb = nxb;
    // no barrier #3: gate_sh/h2rem parity-buffered; hp/c are registers.
  }
}

// K3: feats[t][tag] = b_out[tag] + [hf|hb] . w_out[tag]   (h history is f16)
__global__ void feats_kernel(
    const unsigned short* hstH, const float* w_out, const float* b_out,
    float* feats)
{
  __shared__ float w_sh[12*520];
  __shared__ float h_sh[16*520];
  const _Float16* hf = (const _Float16*)hstH;
  int tid=threadIdx.x;
  int t0=blockIdx.x*16;
  for (int i=tid;i<12*512;i+=256){ int tag=i>>9,k=i&511; w_sh[tag*520+k]=w_out[i]; }
  for (int i=tid;i<16*512;i+=256){
    int tt=i>>9,k=i&511;
    float v = (k<256)? (float)hf[(size_t)(t0+tt)*256+k]
                     : (float)hf[(size_t)(LSEQ+t0+tt)*256 + (k-256)];
    h_sh[tt*520+k]=v;
  }
  __syncthreads();
  if (tid<192){
    int tt=tid/12, tag=tid%12;
    const float* wr=&w_sh[tag*520];
    const float* hr=&h_sh[tt*520];
    float acc=b_out[tag];
    for (int k=0;k<512;k+=4){
      float4 a=*(const float4*)(wr+k);
      float4 b=*(const float4*)(hr+k);
      acc += a.x*b.x+a.y*b.y+a.z*b.z+a.w*b.w;
    }
    feats[(size_t)(t0+tt)*12+tag]=acc;
  }
}

// K4: Viterbi DP: feats in LDS, v register-resident via readlane; parallel
// block-composed backtrack.
__global__ void BiLSTM_CRF_14405320311361_kernel(
    const float* feats, const float* trans, float* outp)
{
  __shared__ float fsh[LSEQ*12];           // 96 KB
  __shared__ unsigned char bps[LSEQ*12];   // 24 KB
  __shared__ float term_sh[16];
  __shared__ int ibuf[66];
  __shared__ unsigned char fmap[64*12];
  int tid = threadIdx.x;
  for (int i=tid; i<LSEQ*12/4; i+=256)
    *(float4*)&fsh[4*i] = *(const float4*)&feats[4*i];
  __syncthreads();

  int lane = tid & 63;
  int fl = (lane<12) ? lane : 0;
  float vn = 0.f;
  if (tid < 64){
    float tr[12];
    #pragma unroll
    for (int p=0;p<12;++p) tr[p] = trans[fl*12+p];
    vn = (lane==10) ? 0.f : -10000.f;     // START=10
    float fa = fsh[fl];
    float fb = fsh[12+fl];
    for (int t=0;t<LSEQ;++t){
      unsigned vu = __float_as_uint(vn);
      float best; int bp; float sc;
      best = tr[0] + __uint_as_float(__builtin_amdgcn_readlane(vu,0)); bp = 0;
      sc = tr[1]  + __uint_as_float(__builtin_amdgcn_readlane(vu,1));  if(sc>best){best=sc;bp=1;}
      sc = tr[2]  + __uint_as_float(__builtin_amdgcn_readlane(vu,2));  if(sc>best){best=sc;bp=2;}
      sc = tr[3]  + __uint_as_float(__builtin_amdgcn_readlane(vu,3));  if(sc>best){best=sc;bp=3;}
      sc = tr[4]  + __uint_as_float(__builtin_amdgcn_readlane(vu,4));  if(sc>best){best=sc;bp=4;}
      sc = tr[5]  + __uint_as_float(__builtin_amdgcn_readlane(vu,5));  if(sc>best){best=sc;bp=5;}
      sc = tr[6]  + __uint_as_float(__builtin_amdgcn_readlane(vu,6));  if(sc>best){best=sc;bp=6;}
      sc = tr[7]  + __uint_as_float(__builtin_amdgcn_readlane(vu,7));  if(sc>best){best=sc;bp=7;}
      sc = tr[8]  + __uint_as_float(__builtin_amdgcn_readlane(vu,8));  if(sc>best){best=sc;bp=8;}
      sc = tr[9]  + __uint_as_float(__builtin_amdgcn_readlane(vu,9));  if(sc>best){best=sc;bp=9;}
      sc = tr[10] + __uint_as_float(__builtin_amdgcn_readlane(vu,10)); if(sc>best){best=sc;bp=10;}
      sc = tr[11] + __uint_as_float(__builtin_amdgcn_readlane(vu,11)); if(sc>best){best=sc;bp=11;}
      vn = best + fa;
      fa = fb;
      if (t+2 < LSEQ) fb = fsh[(t+2)*12+fl];
      if (lane<12) bps[t*12+lane] = (unsigned char)bp;
    }
  }
  if (tid < 12) term_sh[tid] = vn + trans[11*12+tid];   // STOP=11
  __syncthreads();
  if (tid == 0){
    float bs=term_sh[0]; int bt=0;
    for (int p=1;p<12;++p){ if (term_sh[p]>bs){bs=term_sh[p];bt=p;} }
    outp[0] = bs;
    ibuf[64] = bt;
  }
  __syncthreads();
  if (tid < 64){
    int b = tid;
    int f[12];
    int thi = b*32+31;
    #pragma unroll
    for (int x=0;x<12;++x) f[x] = bps[thi*12+x];
    for (int t=thi-1; t>=b*32; --t){
      int base = t*12;
      #pragma unroll
      for (int x=0;x<12;++x) f[x] = bps[base + f[x]];
    }
    #pragma unroll
    for (int x=0;x<12;++x) fmap[b*12+x] = (unsigned char)f[x];
  }
  __syncthreads();
  if (tid == 0){
    int tag = ibuf[64];
    for (int b=63;b>=0;--b){ ibuf[b]=tag; tag = fmap[b*12+tag]; }
  }
  __syncthreads();
  if (tid < 64){
    int b = tid;
    int tag = ibuf[b];
    for (int t=b*32+31; t>=b*32; --t){
      outp[1+t] = (float)tag;
      tag = bps[t*12+tag];
    }
  }
}

extern "C" void kernel_launch(void* const* d_in, const int* in_sizes, int n_in,
                              void* d_out, int out_size, void* d_ws, size_t ws_size,
                              hipStream_t stream) {
  const int*   sent   = (const int*)d_in[0];
  const float* embed  = (const float*)d_in[1];
  const float* w_ih_f = (const float*)d_in[2];
  const float* w_hh_f = (const float*)d_in[3];
  const float* b_ih_f = (const float*)d_in[4];
  const float* b_hh_f = (const float*)d_in[5];
  const float* w_ih_b = (const float*)d_in[6];
  const float* w_hh_b = (const float*)d_in[7];
  const float* b_ih_b = (const float*)d_in[8];
  const float* b_hh_b = (const float*)d_in[9];
  const float* w_out  = (const float*)d_in[10];
  const float* b_out  = (const float*)d_in[11];
  const float* trans  = (const float*)d_in[12];

  float* xg = (float*)d_ws;                                           // [2][L][1024] f32 = 16 MB
  unsigned short* hstH = (unsigned short*)(xg + (size_t)2*LSEQ*1024); // [2][L][256] f16 = 2 MB
  u64* ex = (u64*)(hstH + (size_t)2*LSEQ*256);                        // 8 KB
  float* feats = (float*)(ex + 1024);                                 // [L][12] f32 = 96 KB
  float* outp  = (float*)d_out;

  init_kernel<<<dim3(4), dim3(256), 0, stream>>>(ex);
  xg_kernel<<<dim3(LSEQ/8), dim3(256), 0, stream>>>(
      sent, embed, w_ih_f, b_ih_f, b_hh_f, w_ih_b, b_ih_b, b_hh_b, xg);
  lstm_rec<<<dim3(16), dim3(256), 0, stream>>>(w_hh_f, w_hh_b, xg, hstH, ex);
  feats_kernel<<<dim3(LSEQ/16), dim3(256), 0, stream>>>(hstH, w_out, b_out, feats);
  BiLSTM_CRF_14405320311361_kernel<<<dim3(1), dim3(256), 0, stream>>>(feats, trans, outp);
}